// Round 1
// baseline (114.847 us; speedup 1.0000x reference)
//
#include <hip/hip_runtime.h>
#include <hip/hip_cooperative_groups.h>

namespace cg = cooperative_groups;

#define KLEN 64
#define FCH 16            // fine chunk length (steps)
#define WARMUP 64         // S1 contraction ~0.8/step -> 0.8^64 ~ 6e-7 rel
#define WIN_FC 64         // fine chunks per S2 window (= 1024 steps, one wave)
#define BLOCK 256
#define WPB (BLOCK / 64)  // waves (=windows) per block
#define S1_INIT_V 50.0f
#define S2_INIT_V 250.0f

__device__ __forceinline__ float fpow(float x, float e) {
    // x >= 0; x==0 -> log2=-inf -> exp2=0 (exponents here are > 0)
    return exp2f(e * __log2f(x));
}
__device__ __forceinline__ float clamp01(float x) { return fminf(fmaxf(x, 0.0f), 1.0f); }
__device__ __forceinline__ float physp(const float* raw, int i, float lo, float hi) {
    return lo + (hi - lo) / (1.0f + __expf(-raw[i]));
}

// ---- 8-step forcing group: 24 floats = 6 float4 (16B-aligned when t%8==0) ----
struct F8 { float4 v[6]; };
__device__ __forceinline__ F8 load_f8(const float* __restrict__ forc, int t) {
    const float4* p = (const float4*)(forc + 3 * t);
    F8 r;
#pragma unroll
    for (int k = 0; k < 6; ++k) r.v[k] = p[k];
    return r;
}
__device__ __forceinline__ float f4c(const float4& v, int c) {
    return c == 0 ? v.x : c == 1 ? v.y : c == 2 ? v.z : v.w;
}
__device__ __forceinline__ float f8_get(const F8& f, int i) { return f4c(f.v[i >> 2], i & 3); }

// S1-only step; shares one log2 between the two powers
#define S1_CORE(pr, pe, te, QACC)                                         \
    {                                                                     \
        float rain = (te) > Train ? (pr) : 0.0f;                          \
        float s1f = clamp01(S1 * invS1);                                  \
        float lg = __log2f(s1f);                                          \
        float e1 = (pe)*fminf(s1f * invft, 1.0f);                         \
        float qsx = rain * exp2f(b * lg);                                 \
        float q12 = ku * exp2f(cc * lg);                                  \
        float qif = ki * s1f;                                             \
        S1 = fminf(fmaxf(S1 + rain - qsx - e1 - q12 - qif, 0.0f), S1max); \
        QACC;                                                             \
    }

// ---- Single cooperative kernel: A (S1 spin-up) -> sync -> B (Picard, block-redundant)
// ---- -> C (S2-only finish, q12/qxi cached in regs from A) -> sync -> D (routing conv)
__global__ void __launch_bounds__(BLOCK) k_fused(
        const float* __restrict__ forc, const float* __restrict__ raw,
        float* __restrict__ out,
        float* __restrict__ q12f, float* __restrict__ Qw, float* __restrict__ runoff,
        int T, int nfine) {
    cg::grid_group grid = cg::this_grid();

    __shared__ float S2w_l[128], qbw_l[128];   // window-start S2 / frozen qb (Picard path)
    __shared__ float s2f_l[BLOCK];             // per-chunk S2 starts (fallback path, own block)
    __shared__ float ker[KLEN];
    __shared__ float ls[BLOCK + KLEN - 1];
    __shared__ int flag_l;

    const int tid = threadIdx.x;
    const int lane = tid & 63;
    const int wv = tid >> 6;                   // wave in block
    const int w = blockIdx.x * WPB + wv;       // global window id
    const int j = w * WIN_FC + lane;           // fine chunk id (1 thread : 1 chunk)
    const int NW = (nfine + WIN_FC - 1) / WIN_FC;
    const bool active = j < nfine;

    const float S1max  = physp(raw, 0, 50.0f, 5000.0f);
    const float S2max  = physp(raw, 1, 100.0f, 10000.0f);
    const float f_tens = physp(raw, 2, 0.05f, 0.95f);
    const float ku     = physp(raw, 6, 0.01f, 1000.0f);
    const float cc     = physp(raw, 7, 1.0f, 20.0f);
    const float ki     = physp(raw, 11, 0.01f, 1000.0f);
    const float ks     = physp(raw, 12, 0.001f, 10000.0f);
    const float nn     = physp(raw, 13, 1.0f, 10.0f);
    const float b      = physp(raw, 18, 0.001f, 3.0f);
    const float Train  = physp(raw, 22, -2.0f, 4.0f);
    const float invS1 = 1.0f / S1max, invS2 = 1.0f / S2max, invft = 1.0f / f_tens;

    // ---- Phase A: warmup + main S1 steps; cache per-step q12 and qsx+qif in registers ----
    float q12s[FCH], qxi[FCH];
    float Q = 0.0f;
    if (active) {
        const int t0 = j * FCH;
        const bool full = (t0 + FCH <= T);
        float S1 = S1_INIT_V;
        int ts = max(t0 - WARMUP, 0);
        int ngw = (t0 - ts) >> 3;              // multiple of 8 by construction

        F8 cur = load_f8(forc, ts);            // if ngw==0 this IS the first main group
        for (int g = 0; g < ngw; ++g) {
            F8 nxt = load_f8(forc, ts + 8 * (g + 1));  // last prefetch = first main group
#pragma unroll
            for (int s = 0; s < 8; ++s) {
                float pr = f8_get(cur, 3 * s), pe = f8_get(cur, 3 * s + 1), te = f8_get(cur, 3 * s + 2);
                S1_CORE(pr, pe, te, );
            }
            cur = nxt;
        }
        if (full) {
#pragma unroll
            for (int g = 0; g < FCH / 8; ++g) {
                F8 nxt = cur;
                if (g + 1 < FCH / 8) nxt = load_f8(forc, t0 + 8 * (g + 1));
#pragma unroll
                for (int s = 0; s < 8; ++s) {
                    float pr = f8_get(cur, 3 * s), pe = f8_get(cur, 3 * s + 1), te = f8_get(cur, 3 * s + 2);
                    S1_CORE(pr, pe, te, q12s[8 * g + s] = q12; qxi[8 * g + s] = qsx + qif; Q += q12);
                }
                cur = nxt;
            }
        } else {  // partial tail chunk: scalar guarded loads, static register indices
#pragma unroll
            for (int s = 0; s < FCH; ++s) {
                int t = t0 + s;
                if (t < T) {
                    float pr = forc[3 * t], pe = forc[3 * t + 1], te = forc[3 * t + 2];
                    S1_CORE(pr, pe, te, q12s[s] = q12; qxi[s] = qsx + qif; Q += q12);
                } else {
                    q12s[s] = 0.0f; qxi[s] = 0.0f;
                }
            }
        }
        q12f[j] = Q;  // needed only by the fallback path
    }
    {   // wave-reduce Q -> window inflow
        float sq = Q;
#pragma unroll
        for (int o = 32; o >= 1; o >>= 1) sq += __shfl_xor(sq, o, 64);
        if (lane == 0 && w < NW) Qw[w] = sq;
    }

    grid.sync();

    // ---- Phase B: Picard fixed-point for window-start S2 — redundant per block (wave 0) ----
    if (wv == 0) {
        const int WSTEPS = WIN_FC * FCH;
        int w0 = 2 * lane, w1 = 2 * lane + 1;
        float L0 = (w0 < NW) ? (float)min(WSTEPS, T - WSTEPS * w0) : 0.0f;
        float L1 = (w1 < NW) ? (float)min(WSTEPS, T - WSTEPS * w1) : 0.0f;
        float Q0 = (w0 < NW) ? Qw[w0] : 0.0f;
        float Q1 = (w1 < NW) ? Qw[w1] : 0.0f;

        float qb0 = ks * fpow(clamp01(S2_INIT_V * invS2), nn);
        float qb1 = qb0;
        float S20 = S2_INIT_V, S21 = S2_INIT_V;
        bool picard_ok = (NW <= 128);
        if (picard_ok) {
            for (int it = 0; it < 12; ++it) {
                float d0 = Q0 - L0 * qb0;
                float d1 = Q1 - L1 * qb1;
                float pair = d0 + d1;
                float sc = pair;  // inclusive lane scan
#pragma unroll
                for (int o = 1; o < 64; o <<= 1) {
                    float v = __shfl_up(sc, o, 64);
                    if (lane >= o) sc += v;
                }
                float excl = sc - pair;
                S20 = S2_INIT_V + excl;
                S21 = S20 + d0;
                qb0 = ks * fpow(clamp01(S20 * invS2), nn);
                qb1 = ks * fpow(clamp01(S21 * invS2), nn);
            }
            bool bad = false;
            if (w0 < NW) bad |= (S20 - L0 * qb0 < 0.5f) || (S20 + Q0 > S2max - 0.5f);
            if (w1 < NW) bad |= (S21 - L1 * qb1 < 0.5f) || (S21 + Q1 > S2max - 0.5f);
            picard_ok = (__ballot(bad) == 0ULL);
        }
        if (picard_ok) {
            if (w0 < NW) { S2w_l[w0] = S20; qbw_l[w0] = qb0; }
            if (w1 < NW) { S2w_l[w1] = S21; qbw_l[w1] = qb1; }
            if (lane == 0) flag_l = 0;
        } else if (lane == 0) {
            // exact-ish sequential fallback (clamped, qb frozen per window);
            // deterministic & identical across blocks — each keeps its own chunks' S2 starts
            flag_l = 1;
            float S2 = S2_INIT_V;
            int blk0 = blockIdx.x * BLOCK;  // first chunk owned by this block
            for (int ww = 0; ww < NW; ++ww) {
                float s2fw = clamp01(S2 * invS2);
                float qb = ks * fpow(s2fw, nn);
                int i0 = ww * WIN_FC, i1 = min(i0 + WIN_FC, nfine);
                for (int i = i0; i < i1; ++i) {
                    if ((unsigned)(i - blk0) < (unsigned)BLOCK) s2f_l[i - blk0] = S2;
                    float steps = (float)min(FCH, T - FCH * i);
                    S2 = fminf(fmaxf(S2 + q12f[i] - steps * qb, 0.0f), S2max);
                }
            }
        }
    }
    __syncthreads();

    // ---- Phase C: S2-only finish using cached q12s/qxi; no S1 re-simulation ----
    {
        float sc = Q;  // wave exclusive prefix of window-local q12
#pragma unroll
        for (int o = 1; o < 64; o <<= 1) {
            float v = __shfl_up(sc, o, 64);
            if (lane >= o) sc += v;
        }
        float excl = sc - Q;
        if (active) {
            float S2;
            if (flag_l) {
                S2 = s2f_l[tid];
            } else {
                S2 = S2w_l[w] + excl - qbw_l[w] * (float)(FCH * lane);
                S2 = fminf(fmaxf(S2, 0.0f), S2max);
            }
            int t0 = j * FCH;
            bool full = (t0 + FCH <= T);
            if (full) {
                float ro[FCH];
#pragma unroll
                for (int s = 0; s < FCH; ++s) {
                    float s2f = clamp01(S2 * invS2);
                    float qb = ks * fpow(s2f, nn);
                    ro[s] = qxi[s] + qb;
                    S2 = fminf(fmaxf(S2 + q12s[s] - qb, 0.0f), S2max);
                }
                float4* rp = (float4*)(runoff + t0);
#pragma unroll
                for (int v4 = 0; v4 < FCH / 4; ++v4)
                    rp[v4] = make_float4(ro[4 * v4], ro[4 * v4 + 1], ro[4 * v4 + 2], ro[4 * v4 + 3]);
            } else {
#pragma unroll
                for (int s = 0; s < FCH; ++s) {
                    int t = t0 + s;
                    if (t < T) {
                        float s2f = clamp01(S2 * invS2);
                        float qb = ks * fpow(s2f, nn);
                        runoff[t] = qxi[s] + qb;
                        S2 = fminf(fmaxf(S2 + q12s[s] - qb, 0.0f), S2max);
                    }
                }
            }
        }
    }

    // routing kernel weights (overlap with other blocks still in C; LDS-visible after sync)
    if (tid < 64) {
        float delay = physp(raw, 21, 0.01f, 5.0f);  // mu_t
        float theta = fmaxf(delay, 1e-3f) * (1.0f / 2.5f);
        float tt = (float)tid + 0.5f;
        float logk = 1.5f * __logf(tt) - tt / theta;
        float m = logk;
#pragma unroll
        for (int o = 32; o >= 1; o >>= 1) m = fmaxf(m, __shfl_xor(m, o, 64));
        float e = __expf(logk - m);
        float s = e;
#pragma unroll
        for (int o = 32; o >= 1; o >>= 1) s += __shfl_xor(s, o, 64);
        ker[tid] = e / s;
    }

    grid.sync();

    // ---- Phase D: causal gamma routing conv, grid-strided tiles ----
    int ntile = (T + BLOCK - 1) / BLOCK;
    for (int tile = blockIdx.x; tile < ntile; tile += gridDim.x) {
        int base = tile * BLOCK;
        __syncthreads();  // protect ls from previous tile's readers
        for (int i = tid; i < BLOCK + KLEN - 1; i += BLOCK) {
            int t = base - (KLEN - 1) + i;
            ls[i] = (t >= 0 && t < T) ? runoff[t] : 0.0f;
        }
        __syncthreads();
        float acc = 0.0f;
#pragma unroll
        for (int k = 0; k < KLEN; ++k) acc += ker[k] * ls[tid + (KLEN - 1) - k];
        int t = base + tid;
        if (t < T) out[t] = acc;
    }
}

extern "C" void kernel_launch(void* const* d_in, const int* in_sizes, int n_in,
                              void* d_out, int out_size, void* d_ws, size_t ws_size,
                              hipStream_t stream) {
    const float* forcing = (const float*)d_in[0];  // [T,3]
    const float* raw = (const float*)d_in[1];      // [29]
    float* out = (float*)d_out;
    float* ws = (float*)d_ws;

    int T = in_sizes[0] / 3;
    int nfine = (T + FCH - 1) / FCH;
    int NW = (nfine + WIN_FC - 1) / WIN_FC;
    int nblocks = (NW + WPB - 1) / WPB;  // 32 blocks at T=131072 — trivially co-resident
    if (nblocks < 1) nblocks = 1;

    int P = ((nfine + 7) / 8) * 8;
    int PW = ((NW + 7) / 8) * 8;
    float* q12f = ws;            // [P]  (fallback path only)
    float* Qw = q12f + P;        // [PW]
    float* runoff = Qw + PW;     // [T]

    void* args[] = { (void*)&forcing, (void*)&raw, (void*)&out,
                     (void*)&q12f, (void*)&Qw, (void*)&runoff,
                     (void*)&T, (void*)&nfine };
    hipLaunchCooperativeKernel((const void*)k_fused, dim3(nblocks), dim3(BLOCK),
                               args, 0, stream);
}

// Round 2
// 78.978 us; speedup vs baseline: 1.4542x; 1.4542x over previous
//
#include <hip/hip_runtime.h>

#define KLEN 64
#define FCH 16            // fine chunk length (steps)
#define WARMUP 64         // S1 contraction ~0.8/step -> 0.8^64 ~ 6e-7 rel
#define WIN_FC 64         // fine chunks per S2 window (1024 steps, one wave/block)
#define WSTEPS (WIN_FC * FCH)
#define S1_INIT_V 50.0f
#define S2_INIT_V 250.0f

__device__ __forceinline__ float fpow(float x, float e) {
    // x >= 0; x==0 -> log2=-inf -> exp2=0 (exponents here are > 0)
    return exp2f(e * __log2f(x));
}
__device__ __forceinline__ float clamp01(float x) { return fminf(fmaxf(x, 0.0f), 1.0f); }
__device__ __forceinline__ float physp(const float* raw, int i, float lo, float hi) {
    return lo + (hi - lo) / (1.0f + __expf(-raw[i]));
}
__device__ __forceinline__ float wscan_incl(float x) {  // 64-lane inclusive prefix sum
    float sc = x;
#pragma unroll
    for (int o = 1; o < 64; o <<= 1) {
        float v = __shfl_up(sc, o, 64);
        if ((int)(threadIdx.x & 63) >= o) sc += v;
    }
    return sc;
}

// ---- 8-step forcing group: 24 floats = 6 float4 (16B-aligned when t%8==0) ----
struct F8 { float4 v[6]; };
__device__ __forceinline__ F8 load_f8(const float* __restrict__ forc, int t) {
    const float4* p = (const float4*)(forc + 3 * t);
    F8 r;
#pragma unroll
    for (int k = 0; k < 6; ++k) r.v[k] = p[k];
    return r;
}
__device__ __forceinline__ float f4c(const float4& v, int c) {
    return c == 0 ? v.x : c == 1 ? v.y : c == 2 ? v.z : v.w;
}
__device__ __forceinline__ float f8_get(const F8& f, int i) { return f4c(f.v[i >> 2], i & 3); }

// S1-only step; shares one log2 between the two powers
#define S1_CORE(pr, pe, te, QACC)                                         \
    {                                                                     \
        float rain = (te) > Train ? (pr) : 0.0f;                          \
        float s1f = clamp01(S1 * invS1);                                  \
        float lg = __log2f(s1f);                                          \
        float e1 = (pe)*fminf(s1f * invft, 1.0f);                         \
        float qsx = rain * exp2f(b * lg);                                 \
        float q12 = ku * exp2f(cc * lg);                                  \
        float qif = ki * s1f;                                             \
        S1 = fminf(fmaxf(S1 + rain - qsx - e1 - q12 - qif, 0.0f), S1max); \
        QACC;                                                             \
    }

// ---- Kernel A: per-chunk S1 spin-up + main; persists (q12, qsx+qif) pairs so no
// ---- later kernel ever re-simulates S1. One window (64 chunks) per 64-thread block.
__global__ void __launch_bounds__(64) k_a(
        const float* __restrict__ forc, const float* __restrict__ raw,
        float* __restrict__ qx2, float* __restrict__ q12f, float* __restrict__ Qw,
        int T, int nfine) {
    const int lane = threadIdx.x;
    const int j = blockIdx.x * WIN_FC + lane;
    const bool active = j < nfine;

    const float S1max  = physp(raw, 0, 50.0f, 5000.0f);
    const float f_tens = physp(raw, 2, 0.05f, 0.95f);
    const float ku     = physp(raw, 6, 0.01f, 1000.0f);
    const float cc     = physp(raw, 7, 1.0f, 20.0f);
    const float ki     = physp(raw, 11, 0.01f, 1000.0f);
    const float b      = physp(raw, 18, 0.001f, 3.0f);
    const float Train  = physp(raw, 22, -2.0f, 4.0f);
    const float invS1 = 1.0f / S1max, invft = 1.0f / f_tens;

    float Q = 0.0f;
    if (active) {
        const int t0 = j * FCH;
        const bool full = (t0 + FCH <= T);
        float S1 = S1_INIT_V;
        int ts = max(t0 - WARMUP, 0);
        int ngw = (t0 - ts) >> 3;              // multiple of 8 by construction

        F8 cur = load_f8(forc, ts);            // if ngw==0 this IS the first main group
        for (int g = 0; g < ngw; ++g) {
            F8 nxt = load_f8(forc, ts + 8 * (g + 1));  // last prefetch = first main group
#pragma unroll
            for (int s = 0; s < 8; ++s) {
                float pr = f8_get(cur, 3 * s), pe = f8_get(cur, 3 * s + 1), te = f8_get(cur, 3 * s + 2);
                S1_CORE(pr, pe, te, );
            }
            cur = nxt;
        }
        if (full) {
            float4* qp = (float4*)(qx2 + 32 * j);
#pragma unroll
            for (int g = 0; g < FCH / 8; ++g) {
                F8 nxt = cur;
                if (g + 1 < FCH / 8) nxt = load_f8(forc, t0 + 8 * (g + 1));
                float pg[16];
#pragma unroll
                for (int s = 0; s < 8; ++s) {
                    float pr = f8_get(cur, 3 * s), pe = f8_get(cur, 3 * s + 1), te = f8_get(cur, 3 * s + 2);
                    S1_CORE(pr, pe, te, pg[2 * s] = q12; pg[2 * s + 1] = qsx + qif; Q += q12);
                }
                qp[4 * g + 0] = make_float4(pg[0], pg[1], pg[2], pg[3]);
                qp[4 * g + 1] = make_float4(pg[4], pg[5], pg[6], pg[7]);
                qp[4 * g + 2] = make_float4(pg[8], pg[9], pg[10], pg[11]);
                qp[4 * g + 3] = make_float4(pg[12], pg[13], pg[14], pg[15]);
                cur = nxt;
            }
        } else {  // partial tail chunk: scalar guarded loads, static register indices
#pragma unroll
            for (int s = 0; s < FCH; ++s) {
                int t = t0 + s;
                float a0 = 0.0f, a1 = 0.0f;
                if (t < T) {
                    float pr = forc[3 * t], pe = forc[3 * t + 1], te = forc[3 * t + 2];
                    S1_CORE(pr, pe, te, a0 = q12; a1 = qsx + qif; Q += q12);
                }
                qx2[32 * j + 2 * s] = a0;
                qx2[32 * j + 2 * s + 1] = a1;
            }
        }
        q12f[j] = Q;
    }
    // wave-reduce chunk q12 sums -> window inflow (block == window)
    float sq = Q;
#pragma unroll
    for (int o = 32; o >= 1; o >>= 1) sq += __shfl_xor(sq, o, 64);
    if (lane == 0) Qw[blockIdx.x] = sq;
}

// ---- Kernel BCD: one window per 64-thread block.
// B: Picard for ALL window-start S2 (block-redundant, deterministic -> identical).
// C: per-chunk S2-only finish using stored (q12,qxi) pairs; runoff -> LDS (never global).
//    Lanes 0..3 also redo the previous window's last 4 chunks as the conv halo.
// D: 64-tap gamma conv straight from LDS -> out.
__global__ void __launch_bounds__(64) k_bcd(
        const float* __restrict__ raw, const float* __restrict__ qx2,
        const float* __restrict__ q12f, const float* __restrict__ Qw,
        float* __restrict__ out, int T, int nfine) {
    __shared__ float S2w_l[128], qbw_l[128];
    __shared__ float s2s[4 + WIN_FC];          // [0..3] halo chunk starts, [4..67] own
    __shared__ float ker[KLEN];
    __shared__ float ls[64 + WSTEPS];          // 64-sample halo + this window's runoff
    __shared__ int flag_l;

    const int lane = threadIdx.x;
    const int w = blockIdx.x;
    const int NW = gridDim.x;

    const float S2max = physp(raw, 1, 100.0f, 10000.0f);
    const float ks    = physp(raw, 12, 0.001f, 10000.0f);
    const float nn    = physp(raw, 13, 1.0f, 10.0f);
    const float invS2 = 1.0f / S2max;

    // ---- Phase B: Picard fixed-point (2 windows per lane), redundant per block ----
    {
        int w0 = 2 * lane, w1 = 2 * lane + 1;
        float L0 = (w0 < NW) ? (float)min(WSTEPS, T - WSTEPS * w0) : 0.0f;
        float L1 = (w1 < NW) ? (float)min(WSTEPS, T - WSTEPS * w1) : 0.0f;
        float Q0 = (w0 < NW) ? Qw[w0] : 0.0f;
        float Q1 = (w1 < NW) ? Qw[w1] : 0.0f;

        float qb0 = ks * fpow(clamp01(S2_INIT_V * invS2), nn);
        float qb1 = qb0;
        float S20 = S2_INIT_V, S21 = S2_INIT_V;
        bool ok = (NW <= 128);
        if (ok) {
            for (int it = 0; it < 12; ++it) {
                float d0 = Q0 - L0 * qb0;
                float d1 = Q1 - L1 * qb1;
                float pair = d0 + d1;
                float sc = wscan_incl(pair);
                float excl = sc - pair;
                S20 = S2_INIT_V + excl;
                S21 = S20 + d0;
                qb0 = ks * fpow(clamp01(S20 * invS2), nn);
                qb1 = ks * fpow(clamp01(S21 * invS2), nn);
            }
            bool bad = false;
            if (w0 < NW) bad |= (S20 - L0 * qb0 < 0.5f) || (S20 + Q0 > S2max - 0.5f);
            if (w1 < NW) bad |= (S21 - L1 * qb1 < 0.5f) || (S21 + Q1 > S2max - 0.5f);
            ok = (__ballot(bad) == 0ULL);
        }
        if (ok) {
            if (w0 < NW) { S2w_l[w0] = S20; qbw_l[w0] = qb0; }
            if (w1 < NW) { S2w_l[w1] = S21; qbw_l[w1] = qb1; }
            if (lane == 0) flag_l = 0;
        } else if (lane == 0) {
            // exact-ish sequential fallback (qb frozen per window) — deterministic,
            // identical in every block; only need windows 0..w
            flag_l = 1;
            float S2 = S2_INIT_V;
            for (int ww = 0; ww <= w; ++ww) {
                float qb = ks * fpow(clamp01(S2 * invS2), nn);
                int i0 = ww * WIN_FC, i1 = min(i0 + WIN_FC, nfine);
                for (int i = i0; i < i1; ++i) {
                    int lo = i - i0;
                    if (ww == w) s2s[4 + lo] = S2;
                    if (w > 0 && ww == w - 1 && lo >= WIN_FC - 4) s2s[lo - (WIN_FC - 4)] = S2;
                    float steps = (float)min(FCH, T - FCH * i);
                    S2 = fminf(fmaxf(S2 + q12f[i] - steps * qb, 0.0f), S2max);
                }
            }
        }
    }
    __syncthreads();

    // ---- per-chunk S2 starts via wave prefix of chunk q12 sums (Picard path) ----
    if (!flag_l) {
        {
            int j = w * WIN_FC + lane;
            float qo = (j < nfine) ? q12f[j] : 0.0f;
            float excl = wscan_incl(qo) - qo;
            float v = S2w_l[w] + excl - qbw_l[w] * (float)(FCH * lane);
            s2s[4 + lane] = fminf(fmaxf(v, 0.0f), S2max);
        }
        if (w > 0) {  // previous window's chunks: lanes 60..63 give the 4 halo chunks
            float qh = q12f[(w - 1) * WIN_FC + lane];
            float excl = wscan_incl(qh) - qh;
            if (lane >= WIN_FC - 4) {
                float v = S2w_l[w - 1] + excl - qbw_l[w - 1] * (float)(FCH * lane);
                s2s[lane - (WIN_FC - 4)] = fminf(fmaxf(v, 0.0f), S2max);
            }
        }
    }

    // ---- routing kernel weights (all 64 lanes) ----
    {
        float delay = physp(raw, 21, 0.01f, 5.0f);  // mu_t
        float theta = fmaxf(delay, 1e-3f) * (1.0f / 2.5f);
        float tt = (float)lane + 0.5f;
        float logk = 1.5f * __logf(tt) - tt / theta;
        float m = logk;
#pragma unroll
        for (int o = 32; o >= 1; o >>= 1) m = fmaxf(m, __shfl_xor(m, o, 64));
        float e = __expf(logk - m);
        float s = e;
#pragma unroll
        for (int o = 32; o >= 1; o >>= 1) s += __shfl_xor(s, o, 64);
        ker[lane] = e / s;
    }
    if (w == 0) ls[lane] = 0.0f;  // halo before t=0
    __syncthreads();

    // ---- Phase C: S2-only finish from stored (q12, qsx+qif); runoff into LDS ----
    {
        int j = w * WIN_FC + lane;
        if (j < nfine) {
            float S2 = s2s[4 + lane];
            const float4* qp = (const float4*)(qx2 + 32 * j);
            int t0 = j * FCH;
            if (t0 + FCH <= T) {
                float ro[FCH];
#pragma unroll
                for (int h = 0; h < 8; ++h) {
                    float4 pv = qp[h];
                    {
                        float qb = ks * fpow(clamp01(S2 * invS2), nn);
                        ro[2 * h] = pv.y + qb;
                        S2 = fminf(fmaxf(S2 + pv.x - qb, 0.0f), S2max);
                    }
                    {
                        float qb = ks * fpow(clamp01(S2 * invS2), nn);
                        ro[2 * h + 1] = pv.w + qb;
                        S2 = fminf(fmaxf(S2 + pv.z - qb, 0.0f), S2max);
                    }
                }
                float4* lp = (float4*)&ls[64 + FCH * lane];
                lp[0] = make_float4(ro[0], ro[1], ro[2], ro[3]);
                lp[1] = make_float4(ro[4], ro[5], ro[6], ro[7]);
                lp[2] = make_float4(ro[8], ro[9], ro[10], ro[11]);
                lp[3] = make_float4(ro[12], ro[13], ro[14], ro[15]);
            } else {
#pragma unroll
                for (int s = 0; s < FCH; ++s) {
                    int t = t0 + s;
                    if (t < T) {
                        float q12v = qx2[32 * j + 2 * s], qxiv = qx2[32 * j + 2 * s + 1];
                        float qb = ks * fpow(clamp01(S2 * invS2), nn);
                        ls[64 + FCH * lane + s] = qxiv + qb;
                        S2 = fminf(fmaxf(S2 + q12v - qb, 0.0f), S2max);
                    } else {
                        ls[64 + FCH * lane + s] = 0.0f;
                    }
                }
            }
        } else {
#pragma unroll
            for (int s = 0; s < FCH; ++s) ls[64 + FCH * lane + s] = 0.0f;
        }
        if (w > 0 && lane < 4) {  // halo: previous window's last 4 chunks (always full)
            int c = w * WIN_FC - 4 + lane;
            float S2 = s2s[lane];
            const float4* qp = (const float4*)(qx2 + 32 * c);
#pragma unroll
            for (int h = 0; h < 8; ++h) {
                float4 pv = qp[h];
                {
                    float qb = ks * fpow(clamp01(S2 * invS2), nn);
                    ls[FCH * lane + 2 * h] = pv.y + qb;
                    S2 = fminf(fmaxf(S2 + pv.x - qb, 0.0f), S2max);
                }
                {
                    float qb = ks * fpow(clamp01(S2 * invS2), nn);
                    ls[FCH * lane + 2 * h + 1] = pv.w + qb;
                    S2 = fminf(fmaxf(S2 + pv.z - qb, 0.0f), S2max);
                }
            }
        }
    }
    __syncthreads();

    // ---- Phase D: 64-tap causal conv from LDS; outputs interleaved (lane + 64*s)
    // so every LDS read is lane-consecutive (conflict-free) and stores coalesce.
    float acc[FCH];
#pragma unroll
    for (int s = 0; s < FCH; ++s) acc[s] = 0.0f;
#pragma unroll 4
    for (int m = 0; m < 64; ++m) {
        float km = ker[63 - m];
#pragma unroll
        for (int s = 0; s < FCH; ++s) acc[s] += km * ls[lane + 1 + m + 64 * s];
    }
    int tb = w * WSTEPS;
#pragma unroll
    for (int s = 0; s < FCH; ++s) {
        int t = tb + lane + 64 * s;
        if (t < T) out[t] = acc[s];
    }
}

extern "C" void kernel_launch(void* const* d_in, const int* in_sizes, int n_in,
                              void* d_out, int out_size, void* d_ws, size_t ws_size,
                              hipStream_t stream) {
    const float* forcing = (const float*)d_in[0];  // [T,3]
    const float* raw = (const float*)d_in[1];      // [29]
    float* out = (float*)d_out;
    float* ws = (float*)d_ws;

    int T = in_sizes[0] / 3;
    int nfine = (T + FCH - 1) / FCH;
    int NW = (nfine + WIN_FC - 1) / WIN_FC;
    int P = ((nfine + 7) / 8) * 8;
    int PW = ((NW + 7) / 8) * 8;

    float* qx2 = ws;             // [P*32] interleaved (q12, qsx+qif) per step
    float* q12f = qx2 + (size_t)P * 32;  // [P] per-chunk q12 sums
    float* Qw = q12f + P;        // [PW] per-window inflow

    k_a<<<NW, 64, 0, stream>>>(forcing, raw, qx2, q12f, Qw, T, nfine);
    k_bcd<<<NW, 64, 0, stream>>>(raw, qx2, q12f, Qw, out, T, nfine);
}